// Round 10
// baseline (80.174 us; speedup 1.0000x reference)
//
#include <hip/hip_runtime.h>
#include <math.h>

#define BB 4
#define RR 64
#define SS 512
#define HH 768
#define EE 64
#define SEGD 128
#define NT 6
#define NC 13
#define NP 3
#define NO (NT + NC + NP)        // 22
#define NEGV -1e30f

#define HC 8                     // h-columns per ctx block
#define NHB (HH / HC)            // 96
#define NB_CTX (BB * NHB)        // 384 ctx blocks
#define NB_GATHER (BB * RR)      // 256 gather blocks
#define CTX0 (2 * HH + 2 * SEGD) // 1792 = feature offset of ctx
#define SGF  CTX0                // span+seg feature count

#define OUT_T 0
#define OUT_C (BB * RR * NT)             // 1536
#define OUT_P (BB * RR * (NT + NC))      // 4864

// One kernel, zero inter-block dependencies:
//  blocks [0, NB_CTX): lane=relation masked-max over FULL S for an 8-col h-slice,
//                      then partial logits for those cols -> atomicAdd(out).
//  blocks [NB_CTX, +NB_GATHER): span/seg gather + 1792x22 matvec + bias -> atomicAdd(out).
__global__ __launch_bounds__(256)
void rel_onepass(const float* __restrict__ hidden,     // [B,S,H]
                 const int*   __restrict__ rel_pairs,  // [B,R,2]
                 const int*   __restrict__ rel_masks,  // [B,R,S]
                 const float* __restrict__ span,       // [B,E,H]
                 const float* __restrict__ segs,       // [B,E,SEG]
                 const float* __restrict__ Wt, const float* __restrict__ bt,
                 const float* __restrict__ Wc, const float* __restrict__ bc,
                 const float* __restrict__ Wp, const float* __restrict__ bp,
                 float* __restrict__ out)              // zeroed by memset node
{
    const int bid = blockIdx.x;
    const int t   = threadIdx.x;

    __shared__ unsigned char keep[64 * 516];   // [r][s], stride 516 -> conflict-free
    __shared__ float part[4 * 64 * 9];         // [w][r][j(+1 pad)]
    __shared__ float feat[SGF];                // gather branch
    __shared__ float red[4][NO];

    if (bid < NB_CTX) {
        // ================= ctx branch =================
        const int hc = bid % NHB;
        const int b  = bid / NHB;
        const int h0 = hc * HC;
        const int w  = t >> 6;          // wave: s-window of 128
        const int r  = t & 63;          // lane = relation

        // stage mask bytes (int4-vectorized, coalesced)
        const int* mb = rel_masks + (size_t)b * RR * SS;
        for (int k = t; k < 64 * (SS / 4); k += 256) {
            const int rr = k >> 7;              // k / 128
            const int s4 = (k & 127) * 4;
            const int4 v = *reinterpret_cast<const int4*>(mb + (size_t)rr * SS + s4);
            unsigned char* kp = &keep[rr * 516 + s4];
            kp[0] = (unsigned char)(v.x != 0);
            kp[1] = (unsigned char)(v.y != 0);
            kp[2] = (unsigned char)(v.z != 0);
            kp[3] = (unsigned char)(v.w != 0);
        }
        __syncthreads();

        // masked max over this wave's 128 s-rows; one uniform 32B load per s
        float a0 = -INFINITY, a1 = -INFINITY, a2 = -INFINITY, a3 = -INFINITY;
        float a4 = -INFINITY, a5 = -INFINITY, a6 = -INFINITY, a7 = -INFINITY;
        const float* hp = hidden + ((size_t)b * SS + w * 128) * HH + h0;
        const unsigned char* kp = &keep[r * 516 + w * 128];
#pragma unroll 4
        for (int s = 0; s < 128; ++s) {
            const float4 va = *reinterpret_cast<const float4*>(hp + (size_t)s * HH);
            const float4 vb = *reinterpret_cast<const float4*>(hp + (size_t)s * HH + 4);
            const float a = kp[s] ? 0.f : NEGV;
            a0 = fmaxf(a0, va.x + a);
            a1 = fmaxf(a1, va.y + a);
            a2 = fmaxf(a2, va.z + a);
            a3 = fmaxf(a3, va.w + a);
            a4 = fmaxf(a4, vb.x + a);
            a5 = fmaxf(a5, vb.y + a);
            a6 = fmaxf(a6, vb.z + a);
            a7 = fmaxf(a7, vb.w + a);
        }

        float* pp = &part[(w * 64 + r) * 9];
        pp[0] = a0; pp[1] = a1; pp[2] = a2; pp[3] = a3;
        pp[4] = a4; pp[5] = a5; pp[6] = a6; pp[7] = a7;
        __syncthreads();

        if (w == 0) {
            // cross-wave max -> final ctx for cols [h0, h0+8); zero-fix; matvec; atomics
            float c[HC];
#pragma unroll
            for (int j = 0; j < HC; ++j) {
                float v = part[(0 * 64 + r) * 9 + j];
                v = fmaxf(v, part[(1 * 64 + r) * 9 + j]);
                v = fmaxf(v, part[(2 * 64 + r) * 9 + j]);
                v = fmaxf(v, part[(3 * 64 + r) * 9 + j]);
                c[j] = (v < -1e29f) ? 0.f : v;
            }
            const int br = b * RR + r;
            const int f0 = CTX0 + h0;
            // type
#pragma unroll
            for (int o = 0; o < NT; ++o) {
                float s = 0.f;
#pragma unroll
                for (int j = 0; j < HC; ++j) s += c[j] * Wt[(size_t)(f0 + j) * NT + o];
                atomicAdd(&out[OUT_T + (size_t)br * NT + o], s);
            }
            // cate
#pragma unroll
            for (int o = 0; o < NC; ++o) {
                float s = 0.f;
#pragma unroll
                for (int j = 0; j < HC; ++j) s += c[j] * Wc[(size_t)(f0 + j) * NC + o];
                atomicAdd(&out[OUT_C + (size_t)br * NC + o], s);
            }
            // pola
#pragma unroll
            for (int o = 0; o < NP; ++o) {
                float s = 0.f;
#pragma unroll
                for (int j = 0; j < HC; ++j) s += c[j] * Wp[(size_t)(f0 + j) * NP + o];
                atomicAdd(&out[OUT_P + (size_t)br * NP + o], s);
            }
        }
        return;
    }

    // ================= gather branch: span/seg features + bias =================
    {
        const int br = bid - NB_CTX;
        const int b  = br / RR;

        const int i0 = rel_pairs[(size_t)br * 2 + 0];
        const int i1 = rel_pairs[(size_t)br * 2 + 1];

        const float* sp0 = span + ((size_t)b * EE + i0) * HH;
        const float* sp1 = span + ((size_t)b * EE + i1) * HH;
        feat[t]            = sp0[t];
        feat[t + 256]      = sp0[t + 256];
        feat[t + 512]      = sp0[t + 512];
        feat[HH + t]       = sp1[t];
        feat[HH + t + 256] = sp1[t + 256];
        feat[HH + t + 512] = sp1[t + 512];
        const float* sg0 = segs + ((size_t)b * EE + i0) * SEGD;
        const float* sg1 = segs + ((size_t)b * EE + i1) * SEGD;
        if (t < SEGD) feat[2 * HH + t] = sg0[t];
        else          feat[2 * HH + SEGD + (t - SEGD)] = sg1[t - SEGD];
        __syncthreads();

        float acc[NO];
#pragma unroll
        for (int o = 0; o < NO; ++o) acc[o] = 0.f;
        for (int f = t; f < SGF; f += 256) {      // 7 iters exactly
            const float fv = feat[f];
            const float* wt = Wt + (size_t)f * NT;
            const float* wc = Wc + (size_t)f * NC;
            const float* wp = Wp + (size_t)f * NP;
#pragma unroll
            for (int o = 0; o < NT; ++o) acc[o]           += fv * wt[o];
#pragma unroll
            for (int o = 0; o < NC; ++o) acc[NT + o]      += fv * wc[o];
#pragma unroll
            for (int o = 0; o < NP; ++o) acc[NT + NC + o] += fv * wp[o];
        }
#pragma unroll
        for (int o = 0; o < NO; ++o) {
#pragma unroll
            for (int off = 32; off > 0; off >>= 1)
                acc[o] += __shfl_down(acc[o], off, 64);
        }
        const int wid  = t >> 6;
        const int lane = t & 63;
        if (lane == 0) {
#pragma unroll
            for (int o = 0; o < NO; ++o) red[wid][o] = acc[o];
        }
        __syncthreads();

        if (t < NO) {
            const float v = red[0][t] + red[1][t] + red[2][t] + red[3][t];
            if (t < NT) {
                atomicAdd(&out[OUT_T + (size_t)br * NT + t], v + bt[t]);
            } else if (t < NT + NC) {
                const int o = t - NT;
                atomicAdd(&out[OUT_C + (size_t)br * NC + o], v + bc[o]);
            } else {
                const int o = t - NT - NC;
                atomicAdd(&out[OUT_P + (size_t)br * NP + o], v + bp[o]);
            }
        }
    }
}

extern "C" void kernel_launch(void* const* d_in, const int* in_sizes, int n_in,
                              void* d_out, int out_size, void* d_ws, size_t ws_size,
                              hipStream_t stream) {
    const float* hidden = (const float*)d_in[0];
    const int*   pairs  = (const int*)d_in[1];
    const int*   masks  = (const int*)d_in[2];
    const float* span   = (const float*)d_in[4];
    const float* segs   = (const float*)d_in[5];
    const float* Wt     = (const float*)d_in[6];
    const float* bt     = (const float*)d_in[7];
    const float* Wc     = (const float*)d_in[8];
    const float* bc     = (const float*)d_in[9];
    const float* Wp     = (const float*)d_in[10];
    const float* bp     = (const float*)d_in[11];
    float* out = (float*)d_out;

    // zero the logits (atomicAdd accumulators) — small fill node, graph-safe
    hipMemsetAsync((void*)out, 0, (size_t)out_size * sizeof(float), stream);

    hipLaunchKernelGGL(rel_onepass, dim3(NB_CTX + NB_GATHER), dim3(256), 0, stream,
                       hidden, pairs, masks, span, segs,
                       Wt, bt, Wc, bc, Wp, bp, out);
}

// Round 11
// 30.449 us; speedup vs baseline: 2.6330x; 2.6330x over previous
//
#include <hip/hip_runtime.h>
#include <math.h>

#define BB 4
#define RR 64
#define SS 512
#define HH 768
#define EE 64
#define SEGD 128
#define NT 6
#define NC 13
#define NP 3
#define NO (NT + NC + NP)        // 22
#define REP 2560                 // 2*H + 2*SEG + H
#define CTX0 (2 * HH + 2 * SEGD) // 1792
#define NEGV -1e30f

#define HC 8                     // h-columns per p1 block
#define NHB (HH / HC)            // 96
#define SCP 4                    // s-chunks
#define SROWS (SS / SCP)         // 128
#define NB1 (BB * NHB * SCP)     // 1536 blocks
#define PART_ELEMS ((size_t)BB * RR * SCP * HH)   // 786432 floats (3 MB)

// ---------------- p1: lane=relation masked max (R9-exact, proven) -------------
__global__ __launch_bounds__(256, 6)
void p1_ctx(const float* __restrict__ hidden,      // [B,S,H]
            const int*   __restrict__ rel_masks,   // [B,R,S]
            float* __restrict__ ws)                // [B*R][SCP][HH]
{
    const int bid = blockIdx.x;
    const int sc  = bid & 3;                // SCP = 4
    const int hc  = (bid >> 2) % NHB;
    const int b   = bid / (4 * NHB);
    const int t   = threadIdx.x;
    const int w   = t >> 6;                 // wave id: s-subwindow
    const int r   = t & 63;                 // lane = relation
    const int h0  = hc * HC;
    const int s0  = sc * SROWS;

    __shared__ unsigned char keep[64 * 132];   // [r][s], +4 pad
    __shared__ float part[4 * 64 * 9];         // [w][r][j(+1 pad)]

    const int mbase = b * RR * SS + s0;
    for (int k = t; k < 64 * SROWS; k += 256) {
        const int rr = k >> 7;              // k / 128
        const int s  = k & 127;
        keep[rr * 132 + s] = (unsigned char)(rel_masks[(size_t)mbase + rr * SS + s] != 0);
    }
    __syncthreads();

    float a0 = -INFINITY, a1 = -INFINITY, a2 = -INFINITY, a3 = -INFINITY;
    float a4 = -INFINITY, a5 = -INFINITY, a6 = -INFINITY, a7 = -INFINITY;
    const float* hp = hidden + ((size_t)b * SS + s0 + w * 32) * HH + h0;
    const unsigned char* kp = &keep[r * 132 + w * 32];
#pragma unroll 4
    for (int s = 0; s < 32; ++s) {
        const float4 va = *reinterpret_cast<const float4*>(hp + (size_t)s * HH);
        const float4 vb = *reinterpret_cast<const float4*>(hp + (size_t)s * HH + 4);
        const float a = kp[s] ? 0.f : NEGV;
        a0 = fmaxf(a0, va.x + a);
        a1 = fmaxf(a1, va.y + a);
        a2 = fmaxf(a2, va.z + a);
        a3 = fmaxf(a3, va.w + a);
        a4 = fmaxf(a4, vb.x + a);
        a5 = fmaxf(a5, vb.y + a);
        a6 = fmaxf(a6, vb.z + a);
        a7 = fmaxf(a7, vb.w + a);
    }

    float* pp = &part[(w * 64 + r) * 9];
    pp[0] = a0; pp[1] = a1; pp[2] = a2; pp[3] = a3;
    pp[4] = a4; pp[5] = a5; pp[6] = a6; pp[7] = a7;
    __syncthreads();

    if (w == 0) {
        float* wp = ws + (((size_t)(b * RR + r)) * SCP + sc) * HH + h0;
#pragma unroll
        for (int j = 0; j < 8; ++j) {
            float v = part[(0 * 64 + r) * 9 + j];
            v = fmaxf(v, part[(1 * 64 + r) * 9 + j]);
            v = fmaxf(v, part[(2 * 64 + r) * 9 + j]);
            v = fmaxf(v, part[(3 * 64 + r) * 9 + j]);
            wp[j] = v;
        }
    }
}

// ---------------- p2: 1024 threads, register-features, one sync ----------------
__device__ __forceinline__
float feat_of(int k, int br, int b,
              const float* __restrict__ ws,
              const float* __restrict__ span, const float* __restrict__ segs,
              int i0, int i1)
{
    if (k < HH)            return span[((size_t)b * EE + i0) * HH + k];
    if (k < 2 * HH)        return span[((size_t)b * EE + i1) * HH + (k - HH)];
    if (k < 2 * HH + SEGD) return segs[((size_t)b * EE + i0) * SEGD + (k - 2 * HH)];
    if (k < CTX0)          return segs[((size_t)b * EE + i1) * SEGD + (k - 2 * HH - SEGD)];
    const int col = k - CTX0;
    const float* wb = ws + (size_t)br * SCP * HH + col;
    float m = wb[0];
    m = fmaxf(m, wb[HH]);
    m = fmaxf(m, wb[2 * HH]);
    m = fmaxf(m, wb[3 * HH]);
    return (m < -1e29f) ? 0.f : m;
}

__global__ __launch_bounds__(1024)
void p2_head(const float* __restrict__ ws,          // [B*R][SCP][HH]
             const int*   __restrict__ rel_pairs,   // [B,R,2]
             const float* __restrict__ span,        // [B,E,H]
             const float* __restrict__ segs,        // [B,E,SEG]
             const float* __restrict__ Wt, const float* __restrict__ bt,
             const float* __restrict__ Wc, const float* __restrict__ bc,
             const float* __restrict__ Wp, const float* __restrict__ bp,
             float* __restrict__ out)
{
    const int br = blockIdx.x;
    const int b  = br / RR;
    const int t  = threadIdx.x;

    __shared__ float red[16][NO];

    const int i0 = rel_pairs[(size_t)br * 2 + 0];
    const int i1 = rel_pairs[(size_t)br * 2 + 1];

    // this thread's (up to) 3 feature values, computed straight into registers
    const float fv0 = feat_of(t,        br, b, ws, span, segs, i0, i1);
    const float fv1 = feat_of(t + 1024, br, b, ws, span, segs, i0, i1);
    const bool has2 = (t < 512);   // 64-aligned -> wave-uniform
    const float fv2 = has2 ? feat_of(t + 2048, br, b, ws, span, segs, i0, i1) : 0.f;

    float acc[NO];
#pragma unroll
    for (int o = 0; o < NO; ++o) acc[o] = 0.f;

    {
        const float* wt = Wt + (size_t)t * NT;
        const float* wc = Wc + (size_t)t * NC;
        const float* wp = Wp + (size_t)t * NP;
#pragma unroll
        for (int o = 0; o < NT; ++o) acc[o]           += fv0 * wt[o];
#pragma unroll
        for (int o = 0; o < NC; ++o) acc[NT + o]      += fv0 * wc[o];
#pragma unroll
        for (int o = 0; o < NP; ++o) acc[NT + NC + o] += fv0 * wp[o];
    }
    {
        const int f = t + 1024;
        const float* wt = Wt + (size_t)f * NT;
        const float* wc = Wc + (size_t)f * NC;
        const float* wp = Wp + (size_t)f * NP;
#pragma unroll
        for (int o = 0; o < NT; ++o) acc[o]           += fv1 * wt[o];
#pragma unroll
        for (int o = 0; o < NC; ++o) acc[NT + o]      += fv1 * wc[o];
#pragma unroll
        for (int o = 0; o < NP; ++o) acc[NT + NC + o] += fv1 * wp[o];
    }
    if (has2) {
        const int f = t + 2048;
        const float* wt = Wt + (size_t)f * NT;
        const float* wc = Wc + (size_t)f * NC;
        const float* wp = Wp + (size_t)f * NP;
#pragma unroll
        for (int o = 0; o < NT; ++o) acc[o]           += fv2 * wt[o];
#pragma unroll
        for (int o = 0; o < NC; ++o) acc[NT + o]      += fv2 * wc[o];
#pragma unroll
        for (int o = 0; o < NP; ++o) acc[NT + NC + o] += fv2 * wp[o];
    }

    // wave shuffle reduce (64 lanes) then cross-wave LDS reduce
#pragma unroll
    for (int o = 0; o < NO; ++o) {
#pragma unroll
        for (int off = 32; off > 0; off >>= 1)
            acc[o] += __shfl_down(acc[o], off, 64);
    }
    const int wid  = t >> 6;       // 0..15
    const int lane = t & 63;
    if (lane == 0) {
#pragma unroll
        for (int o = 0; o < NO; ++o) red[wid][o] = acc[o];
    }
    __syncthreads();

    if (t < NO) {
        float v = 0.f;
#pragma unroll
        for (int w = 0; w < 16; ++w) v += red[w][t];
        if (t < NT) {
            out[(size_t)br * NT + t] = v + bt[t];
        } else if (t < NT + NC) {
            const int o = t - NT;
            out[(size_t)BB * RR * NT + (size_t)br * NC + o] = v + bc[o];
        } else {
            const int o = t - NT - NC;
            out[(size_t)BB * RR * (NT + NC) + (size_t)br * NP + o] = v + bp[o];
        }
    }
}

// ---------------- fallback: fused single kernel (if ws too small) ----------------
__global__ __launch_bounds__(256)
void rel_cls_fused(const float* __restrict__ hidden,
                   const int*   __restrict__ rel_pairs,
                   const int*   __restrict__ rel_masks,
                   const float* __restrict__ span,
                   const float* __restrict__ segs,
                   const float* __restrict__ Wt, const float* __restrict__ bt,
                   const float* __restrict__ Wc, const float* __restrict__ bc,
                   const float* __restrict__ Wp, const float* __restrict__ bp,
                   float* __restrict__ out)
{
    const int br = blockIdx.x;
    const int b  = br / RR;
    const int t  = threadIdx.x;

    __shared__ float sadd[SS];
    __shared__ float feat[REP];
    __shared__ float red[4][NO];

    const int* mrow = rel_masks + (size_t)br * SS;
    sadd[t]       = mrow[t] ? 0.f : NEGV;
    sadd[t + 256] = mrow[t + 256] ? 0.f : NEGV;

    const int i0 = rel_pairs[(size_t)br * 2 + 0];
    const int i1 = rel_pairs[(size_t)br * 2 + 1];
    const float* sp0 = span + ((size_t)b * EE + i0) * HH;
    const float* sp1 = span + ((size_t)b * EE + i1) * HH;
    feat[t]            = sp0[t];
    feat[t + 256]      = sp0[t + 256];
    feat[t + 512]      = sp0[t + 512];
    feat[HH + t]       = sp1[t];
    feat[HH + t + 256] = sp1[t + 256];
    feat[HH + t + 512] = sp1[t + 512];
    const float* sg0 = segs + ((size_t)b * EE + i0) * SEGD;
    const float* sg1 = segs + ((size_t)b * EE + i1) * SEGD;
    if (t < SEGD) feat[2 * HH + t] = sg0[t];
    else          feat[2 * HH + SEGD + (t - SEGD)] = sg1[t - SEGD];
    __syncthreads();

    float m0 = -INFINITY, m1 = -INFINITY, m2 = -INFINITY;
#pragma unroll 8
    for (int s = 0; s < SS; ++s) {
        const float* hp = hidden + ((size_t)b * SS + s) * HH;
        const float a = sadd[s];
        m0 = fmaxf(m0, hp[t] + a);
        m1 = fmaxf(m1, hp[t + 256] + a);
        m2 = fmaxf(m2, hp[t + 512] + a);
    }
    if (m0 < -1e29f) m0 = 0.f;
    if (m1 < -1e29f) m1 = 0.f;
    if (m2 < -1e29f) m2 = 0.f;
    feat[CTX0 + t]       = m0;
    feat[CTX0 + t + 256] = m1;
    feat[CTX0 + t + 512] = m2;
    __syncthreads();

    float acc[NO];
#pragma unroll
    for (int o = 0; o < NO; ++o) acc[o] = 0.f;
    for (int f = t; f < REP; f += 256) {
        const float fv = feat[f];
        const float* wt = Wt + (size_t)f * NT;
        const float* wc = Wc + (size_t)f * NC;
        const float* wp = Wp + (size_t)f * NP;
#pragma unroll
        for (int o = 0; o < NT; ++o) acc[o]           += fv * wt[o];
#pragma unroll
        for (int o = 0; o < NC; ++o) acc[NT + o]      += fv * wc[o];
#pragma unroll
        for (int o = 0; o < NP; ++o) acc[NT + NC + o] += fv * wp[o];
    }
#pragma unroll
    for (int o = 0; o < NO; ++o) {
#pragma unroll
        for (int off = 32; off > 0; off >>= 1)
            acc[o] += __shfl_down(acc[o], off, 64);
    }
    const int wid  = t >> 6;
    const int lane = t & 63;
    if (lane == 0) {
#pragma unroll
        for (int o = 0; o < NO; ++o) red[wid][o] = acc[o];
    }
    __syncthreads();

    if (t < NO) {
        const float v = red[0][t] + red[1][t] + red[2][t] + red[3][t];
        if (t < NT) {
            out[(size_t)br * NT + t] = v + bt[t];
        } else if (t < NT + NC) {
            const int o = t - NT;
            out[(size_t)BB * RR * NT + (size_t)br * NC + o] = v + bc[o];
        } else {
            const int o = t - NT - NC;
            out[(size_t)BB * RR * (NT + NC) + (size_t)br * NP + o] = v + bp[o];
        }
    }
}

extern "C" void kernel_launch(void* const* d_in, const int* in_sizes, int n_in,
                              void* d_out, int out_size, void* d_ws, size_t ws_size,
                              hipStream_t stream) {
    const float* hidden = (const float*)d_in[0];
    const int*   pairs  = (const int*)d_in[1];
    const int*   masks  = (const int*)d_in[2];
    const float* span   = (const float*)d_in[4];
    const float* segs   = (const float*)d_in[5];
    const float* Wt     = (const float*)d_in[6];
    const float* bt     = (const float*)d_in[7];
    const float* Wc     = (const float*)d_in[8];
    const float* bc     = (const float*)d_in[9];
    const float* Wp     = (const float*)d_in[10];
    const float* bp     = (const float*)d_in[11];
    float* out = (float*)d_out;
    float* ws  = (float*)d_ws;

    if (ws_size >= PART_ELEMS * sizeof(float)) {
        hipLaunchKernelGGL(p1_ctx, dim3(NB1), dim3(256), 0, stream,
                           hidden, masks, ws);
        hipLaunchKernelGGL(p2_head, dim3(BB * RR), dim3(1024), 0, stream,
                           ws, pairs, span, segs, Wt, bt, Wc, bc, Wp, bp, out);
    } else {
        hipLaunchKernelGGL(rel_cls_fused, dim3(BB * RR), dim3(256), 0, stream,
                           hidden, pairs, masks, span, segs,
                           Wt, bt, Wc, bc, Wp, bp, out);
    }
}

// Round 12
// 29.407 us; speedup vs baseline: 2.7264x; 1.0355x over previous
//
#include <hip/hip_runtime.h>
#include <math.h>

#define BB 4
#define RR 64
#define SS 512
#define HH 768
#define EE 64
#define SEGD 128
#define NT 6
#define NC 13
#define NP 3
#define NO (NT + NC + NP)        // 22
#define REP 2560
#define CTX0 (2 * HH + 2 * SEGD) // 1792
#define NEGV -1e30f

#define RPB 2                    // relations per block
#define NWAVE 8                  // 512 threads = 8 waves
#define SWIN (SS / NWAVE)        // 64 s-rows per wave
#define NBLK (BB * RR / RPB)     // 128 blocks

#define OUT_C (BB * RR * NT)             // 1536
#define OUT_P (BB * RR * (NT + NC))      // 4864

// Single kernel, block-local completeness: each block fully computes 2 relations
// (masked-max over all S + feature gather + 2560x22 matvec) from raw inputs.
// No workspace, no atomics, no cross-block traffic.
__global__ __launch_bounds__(512)
void rel_fused1(const float* __restrict__ hidden,     // [B,S,H]
                const int*   __restrict__ rel_pairs,  // [B,R,2]
                const int*   __restrict__ rel_masks,  // [B,R,S]
                const float* __restrict__ span,       // [B,E,H]
                const float* __restrict__ segs,       // [B,E,SEG]
                const float* __restrict__ Wt, const float* __restrict__ bt,
                const float* __restrict__ Wc, const float* __restrict__ bc,
                const float* __restrict__ Wp, const float* __restrict__ bp,
                float* __restrict__ out)
{
    const int g   = blockIdx.x;
    const int b   = g / (RR / RPB);
    const int rp  = g % (RR / RPB);
    const int br0 = b * RR + rp * RPB;
    const int t   = threadIdx.x;
    const int w   = t >> 6;          // wave id 0..7 : s-window
    const int l   = t & 63;          // lane

    __shared__ float sadd[RPB][SS];          // 4 KB
    __shared__ float part[NWAVE][RPB][HH];   // 48 KB
    __shared__ float red[NWAVE][NO];         // 704 B

    // ---- stage mask addends (coalesced) ----
    for (int k = t; k < RPB * SS; k += 512) {
        const int rel = k >> 9;              // k / 512
        const int s   = k & 511;
        sadd[rel][s] = rel_masks[((size_t)(br0 + rel)) * SS + s] ? 0.f : NEGV;
    }
    __syncthreads();

    // ---- masked max: wave w covers s in [w*64, w*64+64); lane owns 12 cols ----
    float4 m0q0 = make_float4(-INFINITY, -INFINITY, -INFINITY, -INFINITY);
    float4 m0q1 = m0q0, m0q2 = m0q0, m1q0 = m0q0, m1q1 = m0q0, m1q2 = m0q0;

    const float* hrow = hidden + ((size_t)b * SS + w * SWIN) * HH + 4 * l;
    const float* a0p  = &sadd[0][w * SWIN];
    const float* a1p  = &sadd[1][w * SWIN];
#pragma unroll 4
    for (int s = 0; s < SWIN; ++s) {
        const float* hp = hrow + (size_t)s * HH;
        const float4 v0 = *reinterpret_cast<const float4*>(hp);
        const float4 v1 = *reinterpret_cast<const float4*>(hp + 256);
        const float4 v2 = *reinterpret_cast<const float4*>(hp + 512);
        const float a0 = a0p[s];
        const float a1 = a1p[s];
        m0q0.x = fmaxf(m0q0.x, v0.x + a0); m0q0.y = fmaxf(m0q0.y, v0.y + a0);
        m0q0.z = fmaxf(m0q0.z, v0.z + a0); m0q0.w = fmaxf(m0q0.w, v0.w + a0);
        m0q1.x = fmaxf(m0q1.x, v1.x + a0); m0q1.y = fmaxf(m0q1.y, v1.y + a0);
        m0q1.z = fmaxf(m0q1.z, v1.z + a0); m0q1.w = fmaxf(m0q1.w, v1.w + a0);
        m0q2.x = fmaxf(m0q2.x, v2.x + a0); m0q2.y = fmaxf(m0q2.y, v2.y + a0);
        m0q2.z = fmaxf(m0q2.z, v2.z + a0); m0q2.w = fmaxf(m0q2.w, v2.w + a0);
        m1q0.x = fmaxf(m1q0.x, v0.x + a1); m1q0.y = fmaxf(m1q0.y, v0.y + a1);
        m1q0.z = fmaxf(m1q0.z, v0.z + a1); m1q0.w = fmaxf(m1q0.w, v0.w + a1);
        m1q1.x = fmaxf(m1q1.x, v1.x + a1); m1q1.y = fmaxf(m1q1.y, v1.y + a1);
        m1q1.z = fmaxf(m1q1.z, v1.z + a1); m1q1.w = fmaxf(m1q1.w, v1.w + a1);
        m1q2.x = fmaxf(m1q2.x, v2.x + a1); m1q2.y = fmaxf(m1q2.y, v2.y + a1);
        m1q2.z = fmaxf(m1q2.z, v2.z + a1); m1q2.w = fmaxf(m1q2.w, v2.w + a1);
    }

    *reinterpret_cast<float4*>(&part[w][0][      4 * l]) = m0q0;
    *reinterpret_cast<float4*>(&part[w][0][256 + 4 * l]) = m0q1;
    *reinterpret_cast<float4*>(&part[w][0][512 + 4 * l]) = m0q2;
    *reinterpret_cast<float4*>(&part[w][1][      4 * l]) = m1q0;
    *reinterpret_cast<float4*>(&part[w][1][256 + 4 * l]) = m1q1;
    *reinterpret_cast<float4*>(&part[w][1][512 + 4 * l]) = m1q2;
    __syncthreads();

    // ---- matvec: rho = relation (wave-uniform), u = feature phase ----
    const int rho = t >> 8;          // 0..1
    const int u   = t & 255;
    const int br  = br0 + rho;
    const int i0  = rel_pairs[(size_t)br * 2 + 0];
    const int i1  = rel_pairs[(size_t)br * 2 + 1];

    // thread's 10 feature values; feature index f_k = u + 256*k
    float fv[10];
    const float* sp0 = span + ((size_t)b * EE + i0) * HH;
    const float* sp1 = span + ((size_t)b * EE + i1) * HH;
#pragma unroll
    for (int k = 0; k < 3; ++k) fv[k]     = sp0[u + 256 * k];
#pragma unroll
    for (int k = 0; k < 3; ++k) fv[3 + k] = sp1[u + 256 * k];
    fv[6] = (u < SEGD) ? segs[((size_t)b * EE + i0) * SEGD + u]
                       : segs[((size_t)b * EE + i1) * SEGD + (u - SEGD)];
#pragma unroll
    for (int k = 0; k < 3; ++k) {
        const int col = u + 256 * k;
        float m = part[0][rho][col];
#pragma unroll
        for (int ww = 1; ww < NWAVE; ++ww) m = fmaxf(m, part[ww][rho][col]);
        fv[7 + k] = (m < -1e29f) ? 0.f : m;    // all-masked -> reference zeroes
    }

    float acc[NO];
#pragma unroll
    for (int o = 0; o < NO; ++o) acc[o] = 0.f;
#pragma unroll
    for (int k = 0; k < 10; ++k) {
        const float v   = fv[k];
        const size_t f  = (size_t)(u + 256 * k);
        const float* wt = Wt + f * NT;
        const float* wc = Wc + f * NC;
        const float* wp = Wp + f * NP;
#pragma unroll
        for (int o = 0; o < NT; ++o) acc[o]           += v * wt[o];
#pragma unroll
        for (int o = 0; o < NC; ++o) acc[NT + o]      += v * wc[o];
#pragma unroll
        for (int o = 0; o < NP; ++o) acc[NT + NC + o] += v * wp[o];
    }

    // wave shuffle reduce, then cross-wave LDS reduce
#pragma unroll
    for (int o = 0; o < NO; ++o) {
#pragma unroll
        for (int off = 32; off > 0; off >>= 1)
            acc[o] += __shfl_down(acc[o], off, 64);
    }
    if (l == 0) {
#pragma unroll
        for (int o = 0; o < NO; ++o) red[w][o] = acc[o];
    }
    __syncthreads();

    // final: waves 0..3 hold rel0 partials, 4..7 hold rel1
    if (t < RPB * NO) {
        const int rr = t / NO;
        const int o  = t - rr * NO;
        const float v = red[rr * 4 + 0][o] + red[rr * 4 + 1][o]
                      + red[rr * 4 + 2][o] + red[rr * 4 + 3][o];
        const int brx = br0 + rr;
        if (o < NT) {
            out[(size_t)brx * NT + o] = v + bt[o];
        } else if (o < NT + NC) {
            const int oo = o - NT;
            out[OUT_C + (size_t)brx * NC + oo] = v + bc[oo];
        } else {
            const int oo = o - NT - NC;
            out[OUT_P + (size_t)brx * NP + oo] = v + bp[oo];
        }
    }
}

extern "C" void kernel_launch(void* const* d_in, const int* in_sizes, int n_in,
                              void* d_out, int out_size, void* d_ws, size_t ws_size,
                              hipStream_t stream) {
    const float* hidden = (const float*)d_in[0];
    const int*   pairs  = (const int*)d_in[1];
    const int*   masks  = (const int*)d_in[2];
    const float* span   = (const float*)d_in[4];
    const float* segs   = (const float*)d_in[5];
    const float* Wt     = (const float*)d_in[6];
    const float* bt     = (const float*)d_in[7];
    const float* Wc     = (const float*)d_in[8];
    const float* bc     = (const float*)d_in[9];
    const float* Wp     = (const float*)d_in[10];
    const float* bp     = (const float*)d_in[11];
    float* out = (float*)d_out;

    hipLaunchKernelGGL(rel_fused1, dim3(NBLK), dim3(512), 0, stream,
                       hidden, pairs, masks, span, segs,
                       Wt, bt, Wc, bc, Wp, bp, out);
}